// Round 9
// baseline (338.351 us; speedup 1.0000x reference)
//
#include <hip/hip_runtime.h>
#include <hip/hip_bf16.h>

#define BB 4
#define NH 8
#define HD 64
#define CC 512
#define LL 2048
#define KK 1536   // C*3, K index = t*512 + ci
#define LPAD 2050 // padded rows of xT: row 0 and row 2049 are zeros

// softmax scale folded into q-conv: exp(S/64) == exp2(S * log2(e)/64)
#define QS 0.022542110013890054f

typedef float f32x4 __attribute__((ext_vector_type(4)));
typedef short bf16x8 __attribute__((ext_vector_type(8)));

static __device__ __forceinline__ ushort f2bf(float f) {
  union { float f; unsigned u; } v; v.f = f;
  unsigned r = v.u + 0x7fffu + ((v.u >> 16) & 1u);   // RNE
  return (ushort)(r >> 16);
}
static __device__ __forceinline__ void gload16(const ushort* g, ushort* l) {
  __builtin_amdgcn_global_load_lds((const __attribute__((address_space(1))) void*)g,
                                   (__attribute__((address_space(3))) void*)l, 16, 0, 0);
}

// ---------------------------------------------------------------------------
// Weight prep: W[co][ci][t] fp32 -> W'[co][t*512+ci] bf16, for all 4 convs.
// ---------------------------------------------------------------------------
__global__ void prep_w(const float* __restrict__ w0, const float* __restrict__ w1,
                       const float* __restrict__ w2, const float* __restrict__ w3,
                       ushort* __restrict__ out)
{
  int i = blockIdx.x * 256 + threadIdx.x;
  const int per = CC * KK;
  if (i >= 4 * per) return;
  int cidx = i / per;
  int rem  = i - cidx * per;
  int co   = rem / KK;
  int kk   = rem - co * KK;
  int t = kk >> 9, ci = kk & 511;
  const float* w = (cidx == 0) ? w0 : (cidx == 1) ? w1 : (cidx == 2) ? w2 : w3;
  out[i] = f2bf(w[((size_t)co * CC + ci) * 3 + t]);
}

// ---------------------------------------------------------------------------
// Transpose+cast body: xb[c][l] fp32 -> ob[l+1][c] bf16, zero halo rows.
// ---------------------------------------------------------------------------
__device__ __forceinline__ void transpose_body(const float* __restrict__ xb,
                                               ushort* __restrict__ ob)
{
  const int c0 = blockIdx.y * 64;
  const int l0 = blockIdx.x * 64;
  const int tid = threadIdx.x;
  __shared__ ushort T[64 * 72];
  {
    const int rr = tid >> 4;      // 0..15
    const int f4 = tid & 15;      // 0..15
#pragma unroll
    for (int it = 0; it < 4; ++it) {
      const int cc = rr + it * 16;
      ushort s[4];
      float4 vv = *(const float4*)(xb + (size_t)(c0 + cc) * LL + l0 + f4 * 4);
      s[0] = f2bf(vv.x); s[1] = f2bf(vv.y); s[2] = f2bf(vv.z); s[3] = f2bf(vv.w);
      *(ushort4*)&T[cc * 72 + f4 * 4] = *(ushort4*)s;
    }
  }
  __syncthreads();
  {
    const int lr = tid >> 3;     // 0..31
    const int ch = tid & 7;      // 0..7
#pragma unroll
    for (int it = 0; it < 2; ++it) {
      const int ll = lr + it * 32;
      ushort tmp[8];
#pragma unroll
      for (int e = 0; e < 8; ++e) tmp[e] = T[(ch * 8 + e) * 72 + ll];
      *(uint4*)(ob + (size_t)(l0 + ll + 1) * CC + c0 + ch * 8) = *(uint4*)tmp;
    }
  }
  if (blockIdx.x == 0 && tid < 8) {
    uint4 z4 = make_uint4(0, 0, 0, 0);
    *(uint4*)(ob + c0 + tid * 8) = z4;
  }
  if (blockIdx.x == (LL / 64 - 1) && tid >= 248) {
    uint4 z4 = make_uint4(0, 0, 0, 0);
    *(uint4*)(ob + (size_t)(LPAD - 1) * CC + c0 + (tid - 248) * 8) = z4;
  }
}

__global__ __launch_bounds__(256, 4)
void transpose_k(const float* __restrict__ in, ushort* __restrict__ outT)
{
  const int b = blockIdx.z;
  transpose_body(in + (size_t)b * CC * LL, outT + (size_t)b * (LPAD * CC));
}

__global__ __launch_bounds__(256, 4)
void transpose3_k(const float* __restrict__ q, const float* __restrict__ k,
                  const float* __restrict__ v, ushort* __restrict__ xq,
                  ushort* __restrict__ xk, ushort* __restrict__ xv)
{
  const int z = blockIdx.z;
  const int b = z & 3, var = z >> 2;
  const float* in = (var == 0) ? q : (var == 1) ? k : v;
  ushort* out = (var == 0) ? xq : (var == 1) ? xk : xv;
  transpose_body(in + (size_t)b * CC * LL, out + (size_t)b * (LPAD * CC));
}

// ---------------------------------------------------------------------------
// conv1d(k=3,same) as implicit GEMM — ROUND-6 PROVEN STRUCTURE, templated on
// BM (output-channel tile).  BM=128: qkv convs, grid (16,4,12) = 3 blocks/CU.
// BM=64: fc conv, grid (16,8,4) = 512 blocks = 2 blocks/CU.  BK=64,
// single-buffer 2-barrier, (BM/32+4)x global_load_lds(16B)/thread, XOR chunk
// swizzle on the global fetch address, (BM/32)*4*2 MFMA/wave per iter.
// mode 0: heads [b][h][x][d] bf16 (q,k) | 1: heads-T [b][h][d][x] bf16 (v)
// mode 2: [b][co][l] fp32 (final fc)
// scale: folded into epilogue (QS for the q conv so attn can use raw exp2).
// ---------------------------------------------------------------------------
template<int BM>
__device__ __forceinline__ void conv_body(const ushort* __restrict__ xb,
                                          const ushort* __restrict__ Wt,
                                          const float* __restrict__ bias,
                                          void* __restrict__ outp, int mode, int b,
                                          float scale)
{
  const int co0 = blockIdx.y * BM;
  const int l0  = blockIdx.x * 128;
  const int tid = threadIdx.x;
  const int lane = tid & 63;
  const int w    = tid >> 6;
  const int col  = lane & 15, quad = lane >> 4;
  constexpr int MI = BM / 32;              // i-tiles per wave

  __shared__ ushort Asl[BM * 64];
  __shared__ ushort Bsl[128 * 64];

  const int sr = tid >> 3;                 // 0..31
  const int g8 = ((tid & 7) ^ (sr & 7)) * 8;
  const ushort* ag  = Wt + (size_t)(co0 + sr) * KK + g8;
  const ushort* bg  = xb + (size_t)(l0 + sr) * CC + g8;
  ushort* alds = &Asl[tid * 8];
  ushort* blds = &Bsl[tid * 8];

  f32x4 acc[MI][4] = {};
  const int wm = (w & 1) * (BM / 2);
  const int wn = (w >> 1) * 64;
  const int c7 = col & 7;

  for (int k0 = 0; k0 < KK; k0 += 64) {
#pragma unroll
    for (int r2 = 0; r2 < MI; ++r2)
      gload16(ag + (size_t)(r2 * 32) * KK + k0, alds + r2 * 2048);
#pragma unroll
    for (int r2 = 0; r2 < 4; ++r2)
      gload16(bg + (size_t)(r2 * 32) * CC + k0, blds + r2 * 2048);
    __syncthreads();
#pragma unroll
    for (int kk = 0; kk < 2; ++kk) {
      bf16x8 af[MI], bfr[4];
#pragma unroll
      for (int i = 0; i < MI; ++i)
        af[i] = *(const bf16x8*)&Asl[(wm + i * 16 + col) * 64 + (((kk * 4 + quad) ^ c7) * 8)];
#pragma unroll
      for (int j = 0; j < 4; ++j)
        bfr[j] = *(const bf16x8*)&Bsl[(wn + j * 16 + col) * 64 + (((kk * 4 + quad) ^ c7) * 8)];
#pragma unroll
      for (int i = 0; i < MI; ++i)
#pragma unroll
        for (int j = 0; j < 4; ++j)
          acc[i][j] = __builtin_amdgcn_mfma_f32_16x16x32_bf16(af[i], bfr[j], acc[i][j], 0, 0, 0);
    }
    __syncthreads();
  }

  // epilogue: C/D layout row = quad*4+r (co), col = lane&15 (l)
#pragma unroll
  for (int i = 0; i < MI; ++i) {
#pragma unroll
    for (int r = 0; r < 4; ++r) {
      const int co = co0 + wm + i * 16 + quad * 4 + r;
      const float bi = bias[co];
#pragma unroll
      for (int j = 0; j < 4; ++j) {
        const int l = l0 + wn + j * 16 + col;
        const float y = (acc[i][j][r] + bi) * scale;
        if (mode == 0) {
          const int xx = (co << 2) + (l >> 9);
          const int hh = (l >> 6) & 7;
          const int dd = l & 63;
          ((ushort*)outp)[((size_t)(b * NH + hh) * LL + xx) * HD + dd] = f2bf(y);
        } else if (mode == 1) {
          const int xx = (co << 2) + (l >> 9);
          const int hh = (l >> 6) & 7;
          const int dd = l & 63;
          ((ushort*)outp)[((size_t)(b * NH + hh) * HD + dd) * LL + xx] = f2bf(y);
        } else {
          ((float*)outp)[(size_t)(b * CC + co) * LL + l] = y;
        }
      }
    }
  }
}

template<int BM>
__global__ __launch_bounds__(256, 3)
void conv_k(const ushort* __restrict__ xT, const ushort* __restrict__ Wt,
            const float* __restrict__ bias, void* __restrict__ outp, int mode,
            float scale)
{
  const int b = blockIdx.z;
  conv_body<BM>(xT + (size_t)b * (LPAD * CC), Wt, bias, outp, mode, b, scale);
}

__global__ __launch_bounds__(256, 3)
void conv3_k(const ushort* __restrict__ xq, const ushort* __restrict__ xk,
             const ushort* __restrict__ xv, const ushort* __restrict__ Wt,
             const float* __restrict__ b0, const float* __restrict__ b1,
             const float* __restrict__ b2, ushort* __restrict__ o0,
             ushort* __restrict__ o1, ushort* __restrict__ o2)
{
  const int z = blockIdx.z;
  const int b = z & 3, var = z >> 2;
  const ushort* xT = (var == 0) ? xq : (var == 1) ? xk : xv;
  const float* bias = (var == 0) ? b0 : (var == 1) ? b1 : b2;
  ushort* outp = (var == 0) ? o0 : (var == 1) ? o1 : o2;
  const float scale = (var == 0) ? QS : 1.0f;
  conv_body<128>(xT + (size_t)b * (LPAD * CC), Wt + (size_t)var * CC * KK, bias, outp,
                 (var == 2) ? 1 : 0, b, scale);
}

// ---------------------------------------------------------------------------
// Attention v14 = v13 (61.4 us) + V IN REGISTERS (double-buffered, one-tile
// prefetch).  v13 model: tile period 4605 cyc == LDS-pipe work (16 waves x
// ~270 cyc + 384 conflict) -> 100% LDS-saturated; must REMOVE LDS work.
// V's 8 b128 reads/wave/tile (40% of pipe time) move to registers:
//   vf[j][kk] = Vg[(j*16+col)*LL + ybase + kk*32 + quad*8]
// (XOR staging swizzle cancels: LDS[row][c]=glob[row][c^(row&7)], read
// chunk (kk*4+quad)^c7 with row&7==c7 -> global chunk kk*4+quad).  Loads
// for tile t+1 issue at the TOP of tile t (right after K staging issue);
// the compiler's vmcnt(0) drain before the next barrier guarantees
// completion one full tile later -> L2 latency hidden (v8's failure was
// zero prefetch distance).  V staging disappears: Kv halves to 2 x 8 KB.
// Cost: +64 VGPR (vfA/vfB) -> ~120, under the 128 cap for 16 waves/CU.
// Everything else identical to the round-8 PASSED kernel.
// ---------------------------------------------------------------------------
__global__ __launch_bounds__(512, 4)
void attn_k(const ushort* __restrict__ qh, const ushort* __restrict__ kh,
            const ushort* __restrict__ vt, ushort* __restrict__ obT)
{
  const int id   = blockIdx.x;
  const int xcd  = id & 7;
  const int slot = id >> 3;          // 0..63
  const int bh   = xcd * 4 + (slot >> 4);
  const int x0   = (slot & 15) * 128;
  const int b = bh >> 3, h = bh & 7;
  const int tid = threadIdx.x, lane = tid & 63, wv = tid >> 6;   // wv 0..7
  const int col = lane & 15, quad = lane >> 4;
  const int wx = wv * 16;            // wave-private Q rows / P rows
  const int c7 = col & 7;

  __shared__ ushort Kv[2][4096];     // [buf][ K 64x64 ]  16 KB (V no longer staged)
  __shared__ ushort Ps[128 * 88];    // 22.5 KB  (P[x][y], stride 88)

  const ushort* Qg = qh + (size_t)bh * (LL * HD);
  const ushort* Kg = kh + (size_t)bh * (LL * HD);
  const ushort* Vg = vt + (size_t)bh * (HD * LL);
  ushort* ob = obT + (size_t)b * (LPAD * CC);

  const int sr = tid >> 3;                 // 0..63
  const int g8 = ((tid & 7) ^ (sr & 7)) * 8;

  // per-lane V base: row (j*16+col) of V^T, chunk quad
  const ushort* Vgl = Vg + (size_t)col * LL + quad * 8;

  // Q fragments (lane&15 = x-row, k = quad*8+j) — valid as A or B operand
  bf16x8 aq[2];
#pragma unroll
  for (int kk = 0; kk < 2; ++kk)
    aq[kk] = *(const bf16x8*)(Qg + (size_t)(x0 + wx + col) * HD + kk * 32 + quad * 8);

  const short one = (short)0x3F80;  // bf16 1.0
  const bf16x8 ones = {one, one, one, one, one, one, one, one};

  f32x4 oacc[4] = {};
  f32x4 dacc = {};

  bf16x8 vfA[4][2], vfB[4][2];

#define LOAD_VF(vf, ybase)                                                  \
  {                                                                         \
    _Pragma("unroll")                                                       \
    for (int j = 0; j < 4; ++j) {                                           \
      const ushort* p = Vgl + (size_t)j * (16 * LL) + (ybase);              \
      vf[j][0] = *(const bf16x8*)(p);                                       \
      vf[j][1] = *(const bf16x8*)(p + 32);                                  \
    }                                                                       \
  }

#define TILE_COMPUTE(Kb, vf)                                                \
  {                                                                         \
    f32x4 sacc[4] = {};                                                     \
    __builtin_amdgcn_s_setprio(1);                                          \
    _Pragma("unroll")                                                       \
    for (int kk = 0; kk < 2; ++kk)                                          \
      _Pragma("unroll")                                                     \
      for (int j = 0; j < 4; ++j) {                                         \
        bf16x8 bk = *(const bf16x8*)&(Kb)[(j * 16 + col) * 64 +             \
                                          (((kk * 4 + quad) ^ c7) * 8)];    \
        sacc[j] = __builtin_amdgcn_mfma_f32_16x16x32_bf16(bk, aq[kk],       \
                                                          sacc[j], 0, 0, 0);\
      }                                                                     \
    __builtin_amdgcn_s_setprio(0);                                          \
    _Pragma("unroll")                                                       \
    for (int j = 0; j < 4; ++j) {                                           \
      union { __hip_bfloat162 hh[2]; uint2 u; } pk;                         \
      pk.hh[0] = __float22bfloat162_rn(                                     \
          make_float2(__builtin_amdgcn_exp2f(sacc[j][0]),                   \
                      __builtin_amdgcn_exp2f(sacc[j][1])));                 \
      pk.hh[1] = __float22bfloat162_rn(                                     \
          make_float2(__builtin_amdgcn_exp2f(sacc[j][2]),                   \
                      __builtin_amdgcn_exp2f(sacc[j][3])));                 \
      *(uint2*)&Ps[(wx + col) * 88 + j * 16 + quad * 4] = pk.u;             \
    }                                                                       \
    __builtin_amdgcn_s_setprio(1);                                          \
    _Pragma("unroll")                                                       \
    for (int kk = 0; kk < 2; ++kk) {                                        \
      bf16x8 ap = *(const bf16x8*)&Ps[(wx + col) * 88 + kk * 32 + quad * 8];\
      dacc = __builtin_amdgcn_mfma_f32_16x16x32_bf16(ap, ones, dacc,        \
                                                     0, 0, 0);              \
      _Pragma("unroll")                                                     \
      for (int j = 0; j < 4; ++j)                                           \
        oacc[j] = __builtin_amdgcn_mfma_f32_16x16x32_bf16(ap, (vf)[j][kk],  \
                                                          oacc[j], 0, 0, 0);\
    }                                                                       \
    __builtin_amdgcn_s_setprio(0);                                          \
  }

  // prologue: stage K(0) into Kv[0]; V-frags(0) into vfA
  gload16(Kg + (size_t)sr * HD + g8, &Kv[0][tid * 8]);
  LOAD_VF(vfA, 0);

  for (int yt = 0; yt < 32; yt += 2) {
    // ---- even tile yt: Kv[0], vfA ----
    __syncthreads();                       // drains K(yt) staging + vfA loads
    gload16(Kg + (size_t)((yt + 1) * 64 + sr) * HD + g8, &Kv[1][tid * 8]);
    LOAD_VF(vfB, (yt + 1) * 64);
    TILE_COMPUTE(Kv[0], vfA);

    // ---- odd tile yt+1: Kv[1], vfB ----
    __syncthreads();                       // drains K(yt+1) staging + vfB loads
    if (yt + 2 < 32) {
      gload16(Kg + (size_t)((yt + 2) * 64 + sr) * HD + g8, &Kv[0][tid * 8]);
      LOAD_VF(vfA, (yt + 2) * 64);
    }
    TILE_COMPUTE(Kv[1], vfB);
  }
#undef LOAD_VF
#undef TILE_COMPUTE

  // normalize + scatter DIRECTLY to padded-transposed [b][l+1][c] bf16
#pragma unroll
  for (int r = 0; r < 4; ++r) {
    const int xg = x0 + wx + quad * 4 + r;
    const float inv = 1.f / dacc[r];
#pragma unroll
    for (int j = 0; j < 4; ++j) {
      const int d = j * 16 + col;
      const int flat = xg * 512 + h * 64 + d;
      const int c = flat >> 11, l = flat & 2047;
      ob[(size_t)(l + 1) * CC + c] = f2bf(oacc[j][r] * inv);
    }
  }
  if ((slot & 15) == 0 && tid < 128) {
    const int rw = tid >> 6;
    const int cc = h * 64 + (tid & 63);
    ob[(size_t)(rw ? (LPAD - 1) : 0) * CC + cc] = 0;
  }
}

// ---------------------------------------------------------------------------
extern "C" void kernel_launch(void* const* d_in, const int* in_sizes, int n_in,
                              void* d_out, int out_size, void* d_ws, size_t ws_size,
                              hipStream_t stream) {
  const float* q    = (const float*)d_in[0];
  const float* k    = (const float*)d_in[1];
  const float* v    = (const float*)d_in[2];
  const float* wq_w = (const float*)d_in[3];
  const float* wq_b = (const float*)d_in[4];
  const float* wk_w = (const float*)d_in[5];
  const float* wk_b = (const float*)d_in[6];
  const float* wv_w = (const float*)d_in[7];
  const float* wv_b = (const float*)d_in[8];
  const float* fc_w = (const float*)d_in[9];
  const float* fc_b = (const float*)d_in[10];

  char* ws = (char*)d_ws;
  const size_t WSZ = (size_t)CC * KK * sizeof(ushort);            // 1.5 MB per conv
  const size_t HSZ = (size_t)BB * NH * LL * HD * sizeof(ushort);  // 8.39 MB per head tensor
  const size_t XSZ = (size_t)BB * LPAD * CC * sizeof(ushort);     // 8.40 MB padded xT
  const size_t FUSED_NEED = 4 * WSZ + 3 * HSZ + 3 * XSZ;          // ~56.65 MB

  ushort* Wt = (ushort*)(ws);
  prep_w<<<(4 * CC * KK + 255) / 256, 256, 0, stream>>>(wq_w, wk_w, wv_w, fc_w, Wt);

  if (ws_size >= FUSED_NEED) {
    ushort* qh  = (ushort*)(ws + 4 * WSZ);
    ushort* kh  = (ushort*)(ws + 4 * WSZ + HSZ);
    ushort* vt  = (ushort*)(ws + 4 * WSZ + 2 * HSZ);
    ushort* xTq = (ushort*)(ws + 4 * WSZ + 3 * HSZ);
    ushort* xTk = (ushort*)(ws + 4 * WSZ + 3 * HSZ + XSZ);
    ushort* xTv = (ushort*)(ws + 4 * WSZ + 3 * HSZ + 2 * XSZ);
    ushort* obT = xTq;                  // attn output (xTq dead after conv3)

    transpose3_k<<<dim3(32, 8, 12), 256, 0, stream>>>(q, k, v, xTq, xTk, xTv);
    conv3_k<<<dim3(16, 4, 12), 256, 0, stream>>>(xTq, xTk, xTv, Wt,
                                                 wq_b, wk_b, wv_b, qh, kh, vt);
    attn_k<<<512, 512, 0, stream>>>(qh, kh, vt, obT);
    conv_k<64><<<dim3(16, 8, 4), 256, 0, stream>>>(obT, Wt + 3 * CC * KK, fc_b,
                                                   (float*)d_out, 2, 1.0f);
  } else {
    ushort* qh  = (ushort*)(ws + 4 * WSZ);
    ushort* kh  = (ushort*)(ws + 4 * WSZ + HSZ);
    ushort* vt  = (ushort*)(ws + 4 * WSZ + 2 * HSZ);
    ushort* xTb = (ushort*)(ws + 4 * WSZ + 3 * HSZ);
    ushort* obT = xTb;

    transpose_k<<<dim3(32, 8, 4), 256, 0, stream>>>(q, xTb);
    conv_k<128><<<dim3(16, 4, 4), 256, 0, stream>>>(xTb, Wt + 0 * CC * KK, wq_b, qh, 0, QS);
    transpose_k<<<dim3(32, 8, 4), 256, 0, stream>>>(k, xTb);
    conv_k<128><<<dim3(16, 4, 4), 256, 0, stream>>>(xTb, Wt + 1 * CC * KK, wk_b, kh, 0, 1.0f);
    transpose_k<<<dim3(32, 8, 4), 256, 0, stream>>>(v, xTb);
    conv_k<128><<<dim3(16, 4, 4), 256, 0, stream>>>(xTb, Wt + 2 * CC * KK, wv_b, vt, 1, 1.0f);
    attn_k<<<512, 512, 0, stream>>>(qh, kh, vt, obT);
    conv_k<64><<<dim3(16, 8, 4), 256, 0, stream>>>(obT, Wt + 3 * CC * KK, fc_b,
                                                   (float*)d_out, 2, 1.0f);
  }
}

// Round 10
// 280.728 us; speedup vs baseline: 1.2053x; 1.2053x over previous
//
#include <hip/hip_runtime.h>
#include <hip/hip_bf16.h>

#define BB 4
#define NH 8
#define HD 64
#define CC 512
#define LL 2048
#define KK 1536   // C*3, K index = t*512 + ci
#define LPAD 2050 // padded rows of xT: row 0 and row 2049 are zeros

// softmax scale folded into q-conv: exp(S/64) == exp2(S * log2(e)/64)
#define QS 0.022542110013890054f

typedef float f32x4 __attribute__((ext_vector_type(4)));
typedef short bf16x8 __attribute__((ext_vector_type(8)));

static __device__ __forceinline__ ushort f2bf(float f) {
  union { float f; unsigned u; } v; v.f = f;
  unsigned r = v.u + 0x7fffu + ((v.u >> 16) & 1u);   // RNE
  return (ushort)(r >> 16);
}
static __device__ __forceinline__ void gload16(const ushort* g, ushort* l) {
  __builtin_amdgcn_global_load_lds((const __attribute__((address_space(1))) void*)g,
                                   (__attribute__((address_space(3))) void*)l, 16, 0, 0);
}

// ---------------------------------------------------------------------------
// Weight prep: W[co][ci][t] fp32 -> W'[co][t*512+ci] bf16, for all 4 convs.
// ---------------------------------------------------------------------------
__global__ void prep_w(const float* __restrict__ w0, const float* __restrict__ w1,
                       const float* __restrict__ w2, const float* __restrict__ w3,
                       ushort* __restrict__ out)
{
  int i = blockIdx.x * 256 + threadIdx.x;
  const int per = CC * KK;
  if (i >= 4 * per) return;
  int cidx = i / per;
  int rem  = i - cidx * per;
  int co   = rem / KK;
  int kk   = rem - co * KK;
  int t = kk >> 9, ci = kk & 511;
  const float* w = (cidx == 0) ? w0 : (cidx == 1) ? w1 : (cidx == 2) ? w2 : w3;
  out[i] = f2bf(w[((size_t)co * CC + ci) * 3 + t]);
}

// ---------------------------------------------------------------------------
// Transpose+cast body: xb[c][l] fp32 -> ob[l+1][c] bf16, zero halo rows.
// ---------------------------------------------------------------------------
__device__ __forceinline__ void transpose_body(const float* __restrict__ xb,
                                               ushort* __restrict__ ob)
{
  const int c0 = blockIdx.y * 64;
  const int l0 = blockIdx.x * 64;
  const int tid = threadIdx.x;
  __shared__ ushort T[64 * 72];
  {
    const int rr = tid >> 4;      // 0..15
    const int f4 = tid & 15;      // 0..15
#pragma unroll
    for (int it = 0; it < 4; ++it) {
      const int cc = rr + it * 16;
      ushort s[4];
      float4 vv = *(const float4*)(xb + (size_t)(c0 + cc) * LL + l0 + f4 * 4);
      s[0] = f2bf(vv.x); s[1] = f2bf(vv.y); s[2] = f2bf(vv.z); s[3] = f2bf(vv.w);
      *(ushort4*)&T[cc * 72 + f4 * 4] = *(ushort4*)s;
    }
  }
  __syncthreads();
  {
    const int lr = tid >> 3;     // 0..31
    const int ch = tid & 7;      // 0..7
#pragma unroll
    for (int it = 0; it < 2; ++it) {
      const int ll = lr + it * 32;
      ushort tmp[8];
#pragma unroll
      for (int e = 0; e < 8; ++e) tmp[e] = T[(ch * 8 + e) * 72 + ll];
      *(uint4*)(ob + (size_t)(l0 + ll + 1) * CC + c0 + ch * 8) = *(uint4*)tmp;
    }
  }
  if (blockIdx.x == 0 && tid < 8) {
    uint4 z4 = make_uint4(0, 0, 0, 0);
    *(uint4*)(ob + c0 + tid * 8) = z4;
  }
  if (blockIdx.x == (LL / 64 - 1) && tid >= 248) {
    uint4 z4 = make_uint4(0, 0, 0, 0);
    *(uint4*)(ob + (size_t)(LPAD - 1) * CC + c0 + (tid - 248) * 8) = z4;
  }
}

__global__ __launch_bounds__(256, 4)
void transpose_k(const float* __restrict__ in, ushort* __restrict__ outT)
{
  const int b = blockIdx.z;
  transpose_body(in + (size_t)b * CC * LL, outT + (size_t)b * (LPAD * CC));
}

__global__ __launch_bounds__(256, 4)
void transpose3_k(const float* __restrict__ q, const float* __restrict__ k,
                  const float* __restrict__ v, ushort* __restrict__ xq,
                  ushort* __restrict__ xk, ushort* __restrict__ xv)
{
  const int z = blockIdx.z;
  const int b = z & 3, var = z >> 2;
  const float* in = (var == 0) ? q : (var == 1) ? k : v;
  ushort* out = (var == 0) ? xq : (var == 1) ? xk : xv;
  transpose_body(in + (size_t)b * CC * LL, out + (size_t)b * (LPAD * CC));
}

// ---------------------------------------------------------------------------
// conv1d(k=3,same) as implicit GEMM — ROUND-6 PROVEN STRUCTURE, templated on
// BM (output-channel tile).  BM=128: qkv convs, grid (16,4,12) = 3 blocks/CU.
// BM=64: fc conv, grid (16,8,4) = 512 blocks = 2 blocks/CU.  BK=64,
// single-buffer 2-barrier, (BM/32+4)x global_load_lds(16B)/thread, XOR chunk
// swizzle on the global fetch address, (BM/32)*4*2 MFMA/wave per iter.
// mode 0: heads [b][h][x][d] bf16 (q,k) | 1: heads-T [b][h][d][x] bf16 (v)
// mode 2: [b][co][l] fp32 (final fc)
// scale: folded into epilogue (QS for the q conv so attn can use raw exp2).
// ---------------------------------------------------------------------------
template<int BM>
__device__ __forceinline__ void conv_body(const ushort* __restrict__ xb,
                                          const ushort* __restrict__ Wt,
                                          const float* __restrict__ bias,
                                          void* __restrict__ outp, int mode, int b,
                                          float scale)
{
  const int co0 = blockIdx.y * BM;
  const int l0  = blockIdx.x * 128;
  const int tid = threadIdx.x;
  const int lane = tid & 63;
  const int w    = tid >> 6;
  const int col  = lane & 15, quad = lane >> 4;
  constexpr int MI = BM / 32;              // i-tiles per wave

  __shared__ ushort Asl[BM * 64];
  __shared__ ushort Bsl[128 * 64];

  const int sr = tid >> 3;                 // 0..31
  const int g8 = ((tid & 7) ^ (sr & 7)) * 8;
  const ushort* ag  = Wt + (size_t)(co0 + sr) * KK + g8;
  const ushort* bg  = xb + (size_t)(l0 + sr) * CC + g8;
  ushort* alds = &Asl[tid * 8];
  ushort* blds = &Bsl[tid * 8];

  f32x4 acc[MI][4] = {};
  const int wm = (w & 1) * (BM / 2);
  const int wn = (w >> 1) * 64;
  const int c7 = col & 7;

  for (int k0 = 0; k0 < KK; k0 += 64) {
#pragma unroll
    for (int r2 = 0; r2 < MI; ++r2)
      gload16(ag + (size_t)(r2 * 32) * KK + k0, alds + r2 * 2048);
#pragma unroll
    for (int r2 = 0; r2 < 4; ++r2)
      gload16(bg + (size_t)(r2 * 32) * CC + k0, blds + r2 * 2048);
    __syncthreads();
#pragma unroll
    for (int kk = 0; kk < 2; ++kk) {
      bf16x8 af[MI], bfr[4];
#pragma unroll
      for (int i = 0; i < MI; ++i)
        af[i] = *(const bf16x8*)&Asl[(wm + i * 16 + col) * 64 + (((kk * 4 + quad) ^ c7) * 8)];
#pragma unroll
      for (int j = 0; j < 4; ++j)
        bfr[j] = *(const bf16x8*)&Bsl[(wn + j * 16 + col) * 64 + (((kk * 4 + quad) ^ c7) * 8)];
#pragma unroll
      for (int i = 0; i < MI; ++i)
#pragma unroll
        for (int j = 0; j < 4; ++j)
          acc[i][j] = __builtin_amdgcn_mfma_f32_16x16x32_bf16(af[i], bfr[j], acc[i][j], 0, 0, 0);
    }
    __syncthreads();
  }

  // epilogue: C/D layout row = quad*4+r (co), col = lane&15 (l)
#pragma unroll
  for (int i = 0; i < MI; ++i) {
#pragma unroll
    for (int r = 0; r < 4; ++r) {
      const int co = co0 + wm + i * 16 + quad * 4 + r;
      const float bi = bias[co];
#pragma unroll
      for (int j = 0; j < 4; ++j) {
        const int l = l0 + wn + j * 16 + col;
        const float y = (acc[i][j][r] + bi) * scale;
        if (mode == 0) {
          const int xx = (co << 2) + (l >> 9);
          const int hh = (l >> 6) & 7;
          const int dd = l & 63;
          ((ushort*)outp)[((size_t)(b * NH + hh) * LL + xx) * HD + dd] = f2bf(y);
        } else if (mode == 1) {
          const int xx = (co << 2) + (l >> 9);
          const int hh = (l >> 6) & 7;
          const int dd = l & 63;
          ((ushort*)outp)[((size_t)(b * NH + hh) * HD + dd) * LL + xx] = f2bf(y);
        } else {
          ((float*)outp)[(size_t)(b * CC + co) * LL + l] = y;
        }
      }
    }
  }
}

template<int BM>
__global__ __launch_bounds__(256, 3)
void conv_k(const ushort* __restrict__ xT, const ushort* __restrict__ Wt,
            const float* __restrict__ bias, void* __restrict__ outp, int mode,
            float scale)
{
  const int b = blockIdx.z;
  conv_body<BM>(xT + (size_t)b * (LPAD * CC), Wt, bias, outp, mode, b, scale);
}

__global__ __launch_bounds__(256, 3)
void conv3_k(const ushort* __restrict__ xq, const ushort* __restrict__ xk,
             const ushort* __restrict__ xv, const ushort* __restrict__ Wt,
             const float* __restrict__ b0, const float* __restrict__ b1,
             const float* __restrict__ b2, ushort* __restrict__ o0,
             ushort* __restrict__ o1, ushort* __restrict__ o2)
{
  const int z = blockIdx.z;
  const int b = z & 3, var = z >> 2;
  const ushort* xT = (var == 0) ? xq : (var == 1) ? xk : xv;
  const float* bias = (var == 0) ? b0 : (var == 1) ? b1 : b2;
  ushort* outp = (var == 0) ? o0 : (var == 1) ? o1 : o2;
  const float scale = (var == 0) ? QS : 1.0f;
  conv_body<128>(xT + (size_t)b * (LPAD * CC), Wt + (size_t)var * CC * KK, bias, outp,
                 (var == 2) ? 1 : 0, b, scale);
}

// ---------------------------------------------------------------------------
// Attention v15 = v13 (PROVEN 61.4 us) + HALF of V (kk=0) in registers.
// v14 post-mortem: full V-in-reg (64 VGPR x 2 buffers) blew peak pressure
// past the 128 cap -> scratch spills (WRITE_SIZE 2x) -> 156 us.  v15 keeps
// the validated one-tile-ahead prefetch mechanism but halves the footprint:
// vhA/vhB[4] = 32 VGPRs hold only the kk=0 V fragments
//   vh[j] = Vg[(j*16+col)*LL + ybase + quad*8]
// (staging XOR cancels for kk=0: LDS chunk (0*4+quad)^c7 at row&7==c7 ->
// global chunk quad).  kk=1 V reads stay in LDS.  Peak regs ~90 << 128: no
// spills, occupancy stays 16 waves/CU.  LDS b128 reads/wave-tile 18 -> 14;
// modeled LDS-pipe work 4605 -> ~3460 cyc/tile.
// Everything else identical to the round-8 PASSED kernel (setprio included).
// ---------------------------------------------------------------------------
__global__ __launch_bounds__(512, 4)
void attn_k(const ushort* __restrict__ qh, const ushort* __restrict__ kh,
            const ushort* __restrict__ vt, ushort* __restrict__ obT)
{
  const int id   = blockIdx.x;
  const int xcd  = id & 7;
  const int slot = id >> 3;          // 0..63
  const int bh   = xcd * 4 + (slot >> 4);
  const int x0   = (slot & 15) * 128;
  const int b = bh >> 3, h = bh & 7;
  const int tid = threadIdx.x, lane = tid & 63, wv = tid >> 6;   // wv 0..7
  const int col = lane & 15, quad = lane >> 4;
  const int wx = wv * 16;            // wave-private Q rows / P rows
  const int c7 = col & 7;

  __shared__ ushort Kv[2][8192];     // [buf][ K 64x64 | V^T 64x64 ]  32 KB
  __shared__ ushort Ps[128 * 88];    // 22.5 KB  (P[x][y], stride 88)

  const ushort* Qg = qh + (size_t)bh * (LL * HD);
  const ushort* Kg = kh + (size_t)bh * (LL * HD);
  const ushort* Vg = vt + (size_t)bh * (HD * LL);
  ushort* ob = obT + (size_t)b * (LPAD * CC);

  const int sr = tid >> 3;                 // 0..63
  const int g8 = ((tid & 7) ^ (sr & 7)) * 8;

  // per-lane V global base for the kk=0 register fragments
  const ushort* Vgl = Vg + (size_t)col * LL + quad * 8;

  // Q fragments (lane&15 = x-row, k = quad*8+j) — valid as A or B operand
  bf16x8 aq[2];
#pragma unroll
  for (int kk = 0; kk < 2; ++kk)
    aq[kk] = *(const bf16x8*)(Qg + (size_t)(x0 + wx + col) * HD + kk * 32 + quad * 8);

  const short one = (short)0x3F80;  // bf16 1.0
  const bf16x8 ones = {one, one, one, one, one, one, one, one};

  f32x4 oacc[4] = {};
  f32x4 dacc = {};

  bf16x8 vhA[4], vhB[4];

#define LOAD_VH(vh, ybase)                                                  \
  {                                                                         \
    _Pragma("unroll")                                                       \
    for (int j = 0; j < 4; ++j)                                             \
      vh[j] = *(const bf16x8*)(Vgl + (size_t)j * (16 * LL) + (ybase));      \
  }

#define TILE_COMPUTE(Kb, Vb, vh)                                            \
  {                                                                         \
    f32x4 sacc[4] = {};                                                     \
    __builtin_amdgcn_s_setprio(1);                                          \
    _Pragma("unroll")                                                       \
    for (int kk = 0; kk < 2; ++kk)                                          \
      _Pragma("unroll")                                                     \
      for (int j = 0; j < 4; ++j) {                                         \
        bf16x8 bk = *(const bf16x8*)&(Kb)[(j * 16 + col) * 64 +             \
                                          (((kk * 4 + quad) ^ c7) * 8)];    \
        sacc[j] = __builtin_amdgcn_mfma_f32_16x16x32_bf16(bk, aq[kk],       \
                                                          sacc[j], 0, 0, 0);\
      }                                                                     \
    __builtin_amdgcn_s_setprio(0);                                          \
    _Pragma("unroll")                                                       \
    for (int j = 0; j < 4; ++j) {                                           \
      union { __hip_bfloat162 hh[2]; uint2 u; } pk;                         \
      pk.hh[0] = __float22bfloat162_rn(                                     \
          make_float2(__builtin_amdgcn_exp2f(sacc[j][0]),                   \
                      __builtin_amdgcn_exp2f(sacc[j][1])));                 \
      pk.hh[1] = __float22bfloat162_rn(                                     \
          make_float2(__builtin_amdgcn_exp2f(sacc[j][2]),                   \
                      __builtin_amdgcn_exp2f(sacc[j][3])));                 \
      *(uint2*)&Ps[(wx + col) * 88 + j * 16 + quad * 4] = pk.u;             \
    }                                                                       \
    __builtin_amdgcn_s_setprio(1);                                          \
    {                                                                       \
      /* kk = 0: V from registers */                                        \
      bf16x8 ap = *(const bf16x8*)&Ps[(wx + col) * 88 + quad * 8];          \
      dacc = __builtin_amdgcn_mfma_f32_16x16x32_bf16(ap, ones, dacc,        \
                                                     0, 0, 0);              \
      _Pragma("unroll")                                                     \
      for (int j = 0; j < 4; ++j)                                           \
        oacc[j] = __builtin_amdgcn_mfma_f32_16x16x32_bf16(ap, (vh)[j],      \
                                                          oacc[j], 0, 0, 0);\
    }                                                                       \
    {                                                                       \
      /* kk = 1: V from LDS */                                              \
      bf16x8 ap = *(const bf16x8*)&Ps[(wx + col) * 88 + 32 + quad * 8];     \
      dacc = __builtin_amdgcn_mfma_f32_16x16x32_bf16(ap, ones, dacc,        \
                                                     0, 0, 0);              \
      _Pragma("unroll")                                                     \
      for (int j = 0; j < 4; ++j) {                                         \
        bf16x8 bv = *(const bf16x8*)&(Vb)[(j * 16 + col) * 64 +             \
                                          (((4 + quad) ^ c7) * 8)];         \
        oacc[j] = __builtin_amdgcn_mfma_f32_16x16x32_bf16(ap, bv,           \
                                                          oacc[j], 0, 0, 0);\
      }                                                                     \
    }                                                                       \
    __builtin_amdgcn_s_setprio(0);                                          \
  }

  // prologue: stage K(0)/V(0) into buf 0; kk=0 V frags of tile 0 into vhA
  gload16(Kg + (size_t)sr * HD + g8, &Kv[0][tid * 8]);
  gload16(Vg + (size_t)sr * LL + g8, &Kv[0][4096 + tid * 8]);
  LOAD_VH(vhA, 0);

  for (int yt = 0; yt < 32; yt += 2) {
    // ---- even tile yt: buf 0, vhA ----
    __syncthreads();                 // vmcnt(0) drain: staging(yt) + vhA done
    {
      const int y1 = (yt + 1) * 64;
      gload16(Kg + (size_t)(y1 + sr) * HD + g8, &Kv[1][tid * 8]);
      gload16(Vg + (size_t)sr * LL + y1 + g8, &Kv[1][4096 + tid * 8]);
      LOAD_VH(vhB, y1);
    }
    TILE_COMPUTE(Kv[0], (&Kv[0][4096]), vhA);

    // ---- odd tile yt+1: buf 1, vhB ----
    __syncthreads();                 // drain: staging(yt+1) + vhB done
    if (yt + 2 < 32) {
      const int y2 = (yt + 2) * 64;
      gload16(Kg + (size_t)(y2 + sr) * HD + g8, &Kv[0][tid * 8]);
      gload16(Vg + (size_t)sr * LL + y2 + g8, &Kv[0][4096 + tid * 8]);
      LOAD_VH(vhA, y2);
    }
    TILE_COMPUTE(Kv[1], (&Kv[1][4096]), vhB);
  }
#undef LOAD_VH
#undef TILE_COMPUTE

  // normalize + scatter DIRECTLY to padded-transposed [b][l+1][c] bf16
#pragma unroll
  for (int r = 0; r < 4; ++r) {
    const int xg = x0 + wx + quad * 4 + r;
    const float inv = 1.f / dacc[r];
#pragma unroll
    for (int j = 0; j < 4; ++j) {
      const int d = j * 16 + col;
      const int flat = xg * 512 + h * 64 + d;
      const int c = flat >> 11, l = flat & 2047;
      ob[(size_t)(l + 1) * CC + c] = f2bf(oacc[j][r] * inv);
    }
  }
  if ((slot & 15) == 0 && tid < 128) {
    const int rw = tid >> 6;
    const int cc = h * 64 + (tid & 63);
    ob[(size_t)(rw ? (LPAD - 1) : 0) * CC + cc] = 0;
  }
}

// ---------------------------------------------------------------------------
extern "C" void kernel_launch(void* const* d_in, const int* in_sizes, int n_in,
                              void* d_out, int out_size, void* d_ws, size_t ws_size,
                              hipStream_t stream) {
  const float* q    = (const float*)d_in[0];
  const float* k    = (const float*)d_in[1];
  const float* v    = (const float*)d_in[2];
  const float* wq_w = (const float*)d_in[3];
  const float* wq_b = (const float*)d_in[4];
  const float* wk_w = (const float*)d_in[5];
  const float* wk_b = (const float*)d_in[6];
  const float* wv_w = (const float*)d_in[7];
  const float* wv_b = (const float*)d_in[8];
  const float* fc_w = (const float*)d_in[9];
  const float* fc_b = (const float*)d_in[10];

  char* ws = (char*)d_ws;
  const size_t WSZ = (size_t)CC * KK * sizeof(ushort);            // 1.5 MB per conv
  const size_t HSZ = (size_t)BB * NH * LL * HD * sizeof(ushort);  // 8.39 MB per head tensor
  const size_t XSZ = (size_t)BB * LPAD * CC * sizeof(ushort);     // 8.40 MB padded xT
  const size_t FUSED_NEED = 4 * WSZ + 3 * HSZ + 3 * XSZ;          // ~56.65 MB

  ushort* Wt = (ushort*)(ws);
  prep_w<<<(4 * CC * KK + 255) / 256, 256, 0, stream>>>(wq_w, wk_w, wv_w, fc_w, Wt);

  if (ws_size >= FUSED_NEED) {
    ushort* qh  = (ushort*)(ws + 4 * WSZ);
    ushort* kh  = (ushort*)(ws + 4 * WSZ + HSZ);
    ushort* vt  = (ushort*)(ws + 4 * WSZ + 2 * HSZ);
    ushort* xTq = (ushort*)(ws + 4 * WSZ + 3 * HSZ);
    ushort* xTk = (ushort*)(ws + 4 * WSZ + 3 * HSZ + XSZ);
    ushort* xTv = (ushort*)(ws + 4 * WSZ + 3 * HSZ + 2 * XSZ);
    ushort* obT = xTq;                  // attn output (xTq dead after conv3)

    transpose3_k<<<dim3(32, 8, 12), 256, 0, stream>>>(q, k, v, xTq, xTk, xTv);
    conv3_k<<<dim3(16, 4, 12), 256, 0, stream>>>(xTq, xTk, xTv, Wt,
                                                 wq_b, wk_b, wv_b, qh, kh, vt);
    attn_k<<<512, 512, 0, stream>>>(qh, kh, vt, obT);
    conv_k<64><<<dim3(16, 8, 4), 256, 0, stream>>>(obT, Wt + 3 * CC * KK, fc_b,
                                                   (float*)d_out, 2, 1.0f);
  } else {
    ushort* qh  = (ushort*)(ws + 4 * WSZ);
    ushort* kh  = (ushort*)(ws + 4 * WSZ + HSZ);
    ushort* vt  = (ushort*)(ws + 4 * WSZ + 2 * HSZ);
    ushort* xTb = (ushort*)(ws + 4 * WSZ + 3 * HSZ);
    ushort* obT = xTb;

    transpose_k<<<dim3(32, 8, 4), 256, 0, stream>>>(q, xTb);
    conv_k<128><<<dim3(16, 4, 4), 256, 0, stream>>>(xTb, Wt + 0 * CC * KK, wq_b, qh, 0, QS);
    transpose_k<<<dim3(32, 8, 4), 256, 0, stream>>>(k, xTb);
    conv_k<128><<<dim3(16, 4, 4), 256, 0, stream>>>(xTb, Wt + 1 * CC * KK, wk_b, kh, 0, 1.0f);
    transpose_k<<<dim3(32, 8, 4), 256, 0, stream>>>(v, xTb);
    conv_k<128><<<dim3(16, 4, 4), 256, 0, stream>>>(xTb, Wt + 2 * CC * KK, wv_b, vt, 1, 1.0f);
    attn_k<<<512, 512, 0, stream>>>(qh, kh, vt, obT);
    conv_k<64><<<dim3(16, 8, 4), 256, 0, stream>>>(obT, Wt + 3 * CC * KK, fc_b,
                                                   (float*)d_out, 2, 1.0f);
  }
}

// Round 11
// 255.952 us; speedup vs baseline: 1.3219x; 1.0968x over previous
//
#include <hip/hip_runtime.h>
#include <hip/hip_bf16.h>

#define BB 4
#define NH 8
#define HD 64
#define CC 512
#define LL 2048
#define KK 1536   // C*3, K index = t*512 + ci
#define LPAD 2050 // padded rows of xT: row 0 and row 2049 are zeros

// softmax scale folded into q-conv: exp(S/64) == exp2(S * log2(e)/64)
#define QS 0.022542110013890054f

typedef float f32x4 __attribute__((ext_vector_type(4)));
typedef short bf16x8 __attribute__((ext_vector_type(8)));

static __device__ __forceinline__ ushort f2bf(float f) {
  union { float f; unsigned u; } v; v.f = f;
  unsigned r = v.u + 0x7fffu + ((v.u >> 16) & 1u);   // RNE
  return (ushort)(r >> 16);
}
static __device__ __forceinline__ void gload16(const ushort* g, ushort* l) {
  __builtin_amdgcn_global_load_lds((const __attribute__((address_space(1))) void*)g,
                                   (__attribute__((address_space(3))) void*)l, 16, 0, 0);
}

// ---------------------------------------------------------------------------
// Weight prep: W[co][ci][t] fp32 -> W'[co][t*512+ci] bf16, for all 4 convs.
// ---------------------------------------------------------------------------
__global__ void prep_w(const float* __restrict__ w0, const float* __restrict__ w1,
                       const float* __restrict__ w2, const float* __restrict__ w3,
                       ushort* __restrict__ out)
{
  int i = blockIdx.x * 256 + threadIdx.x;
  const int per = CC * KK;
  if (i >= 4 * per) return;
  int cidx = i / per;
  int rem  = i - cidx * per;
  int co   = rem / KK;
  int kk   = rem - co * KK;
  int t = kk >> 9, ci = kk & 511;
  const float* w = (cidx == 0) ? w0 : (cidx == 1) ? w1 : (cidx == 2) ? w2 : w3;
  out[i] = f2bf(w[((size_t)co * CC + ci) * 3 + t]);
}

// ---------------------------------------------------------------------------
// Transpose+cast body: xb[c][l] fp32 -> ob[l+1][c] bf16, zero halo rows.
// ---------------------------------------------------------------------------
__device__ __forceinline__ void transpose_body(const float* __restrict__ xb,
                                               ushort* __restrict__ ob)
{
  const int c0 = blockIdx.y * 64;
  const int l0 = blockIdx.x * 64;
  const int tid = threadIdx.x;
  __shared__ ushort T[64 * 72];
  {
    const int rr = tid >> 4;      // 0..15
    const int f4 = tid & 15;      // 0..15
#pragma unroll
    for (int it = 0; it < 4; ++it) {
      const int cc = rr + it * 16;
      ushort s[4];
      float4 vv = *(const float4*)(xb + (size_t)(c0 + cc) * LL + l0 + f4 * 4);
      s[0] = f2bf(vv.x); s[1] = f2bf(vv.y); s[2] = f2bf(vv.z); s[3] = f2bf(vv.w);
      *(ushort4*)&T[cc * 72 + f4 * 4] = *(ushort4*)s;
    }
  }
  __syncthreads();
  {
    const int lr = tid >> 3;     // 0..31
    const int ch = tid & 7;      // 0..7
#pragma unroll
    for (int it = 0; it < 2; ++it) {
      const int ll = lr + it * 32;
      ushort tmp[8];
#pragma unroll
      for (int e = 0; e < 8; ++e) tmp[e] = T[(ch * 8 + e) * 72 + ll];
      *(uint4*)(ob + (size_t)(l0 + ll + 1) * CC + c0 + ch * 8) = *(uint4*)tmp;
    }
  }
  if (blockIdx.x == 0 && tid < 8) {
    uint4 z4 = make_uint4(0, 0, 0, 0);
    *(uint4*)(ob + c0 + tid * 8) = z4;
  }
  if (blockIdx.x == (LL / 64 - 1) && tid >= 248) {
    uint4 z4 = make_uint4(0, 0, 0, 0);
    *(uint4*)(ob + (size_t)(LPAD - 1) * CC + c0 + (tid - 248) * 8) = z4;
  }
}

__global__ __launch_bounds__(256, 4)
void transpose_k(const float* __restrict__ in, ushort* __restrict__ outT)
{
  const int b = blockIdx.z;
  transpose_body(in + (size_t)b * CC * LL, outT + (size_t)b * (LPAD * CC));
}

__global__ __launch_bounds__(256, 4)
void transpose3_k(const float* __restrict__ q, const float* __restrict__ k,
                  const float* __restrict__ v, ushort* __restrict__ xq,
                  ushort* __restrict__ xk, ushort* __restrict__ xv)
{
  const int z = blockIdx.z;
  const int b = z & 3, var = z >> 2;
  const float* in = (var == 0) ? q : (var == 1) ? k : v;
  ushort* out = (var == 0) ? xq : (var == 1) ? xk : xv;
  transpose_body(in + (size_t)b * CC * LL, out + (size_t)b * (LPAD * CC));
}

// ---------------------------------------------------------------------------
// conv1d(k=3,same) as implicit GEMM — ROUND-6 PROVEN STRUCTURE, templated on
// BM (output-channel tile).  BM=128: qkv convs, grid (16,4,12) = 3 blocks/CU.
// BM=64: fc conv, grid (16,8,4) = 512 blocks = 2 blocks/CU.  BK=64,
// single-buffer 2-barrier, (BM/32+4)x global_load_lds(16B)/thread, XOR chunk
// swizzle on the global fetch address, (BM/32)*4*2 MFMA/wave per iter.
// mode 0: heads [b][h][x][d] bf16 (q,k) | 1: heads-T [b][h][d][x] bf16 (v)
// mode 2: [b][co][l] fp32 (final fc)
// scale: folded into epilogue (QS for the q conv so attn can use raw exp2).
// ---------------------------------------------------------------------------
template<int BM>
__device__ __forceinline__ void conv_body(const ushort* __restrict__ xb,
                                          const ushort* __restrict__ Wt,
                                          const float* __restrict__ bias,
                                          void* __restrict__ outp, int mode, int b,
                                          float scale)
{
  const int co0 = blockIdx.y * BM;
  const int l0  = blockIdx.x * 128;
  const int tid = threadIdx.x;
  const int lane = tid & 63;
  const int w    = tid >> 6;
  const int col  = lane & 15, quad = lane >> 4;
  constexpr int MI = BM / 32;              // i-tiles per wave

  __shared__ ushort Asl[BM * 64];
  __shared__ ushort Bsl[128 * 64];

  const int sr = tid >> 3;                 // 0..31
  const int g8 = ((tid & 7) ^ (sr & 7)) * 8;
  const ushort* ag  = Wt + (size_t)(co0 + sr) * KK + g8;
  const ushort* bg  = xb + (size_t)(l0 + sr) * CC + g8;
  ushort* alds = &Asl[tid * 8];
  ushort* blds = &Bsl[tid * 8];

  f32x4 acc[MI][4] = {};
  const int wm = (w & 1) * (BM / 2);
  const int wn = (w >> 1) * 64;
  const int c7 = col & 7;

  for (int k0 = 0; k0 < KK; k0 += 64) {
#pragma unroll
    for (int r2 = 0; r2 < MI; ++r2)
      gload16(ag + (size_t)(r2 * 32) * KK + k0, alds + r2 * 2048);
#pragma unroll
    for (int r2 = 0; r2 < 4; ++r2)
      gload16(bg + (size_t)(r2 * 32) * CC + k0, blds + r2 * 2048);
    __syncthreads();
#pragma unroll
    for (int kk = 0; kk < 2; ++kk) {
      bf16x8 af[MI], bfr[4];
#pragma unroll
      for (int i = 0; i < MI; ++i)
        af[i] = *(const bf16x8*)&Asl[(wm + i * 16 + col) * 64 + (((kk * 4 + quad) ^ c7) * 8)];
#pragma unroll
      for (int j = 0; j < 4; ++j)
        bfr[j] = *(const bf16x8*)&Bsl[(wn + j * 16 + col) * 64 + (((kk * 4 + quad) ^ c7) * 8)];
#pragma unroll
      for (int i = 0; i < MI; ++i)
#pragma unroll
        for (int j = 0; j < 4; ++j)
          acc[i][j] = __builtin_amdgcn_mfma_f32_16x16x32_bf16(af[i], bfr[j], acc[i][j], 0, 0, 0);
    }
    __syncthreads();
  }

  // epilogue: C/D layout row = quad*4+r (co), col = lane&15 (l)
#pragma unroll
  for (int i = 0; i < MI; ++i) {
#pragma unroll
    for (int r = 0; r < 4; ++r) {
      const int co = co0 + wm + i * 16 + quad * 4 + r;
      const float bi = bias[co];
#pragma unroll
      for (int j = 0; j < 4; ++j) {
        const int l = l0 + wn + j * 16 + col;
        const float y = (acc[i][j][r] + bi) * scale;
        if (mode == 0) {
          const int xx = (co << 2) + (l >> 9);
          const int hh = (l >> 6) & 7;
          const int dd = l & 63;
          ((ushort*)outp)[((size_t)(b * NH + hh) * LL + xx) * HD + dd] = f2bf(y);
        } else if (mode == 1) {
          const int xx = (co << 2) + (l >> 9);
          const int hh = (l >> 6) & 7;
          const int dd = l & 63;
          ((ushort*)outp)[((size_t)(b * NH + hh) * HD + dd) * LL + xx] = f2bf(y);
        } else {
          ((float*)outp)[(size_t)(b * CC + co) * LL + l] = y;
        }
      }
    }
  }
}

template<int BM>
__global__ __launch_bounds__(256, 3)
void conv_k(const ushort* __restrict__ xT, const ushort* __restrict__ Wt,
            const float* __restrict__ bias, void* __restrict__ outp, int mode,
            float scale)
{
  const int b = blockIdx.z;
  conv_body<BM>(xT + (size_t)b * (LPAD * CC), Wt, bias, outp, mode, b, scale);
}

__global__ __launch_bounds__(256, 3)
void conv3_k(const ushort* __restrict__ xq, const ushort* __restrict__ xk,
             const ushort* __restrict__ xv, const ushort* __restrict__ Wt,
             const float* __restrict__ b0, const float* __restrict__ b1,
             const float* __restrict__ b2, ushort* __restrict__ o0,
             ushort* __restrict__ o1, ushort* __restrict__ o2)
{
  const int z = blockIdx.z;
  const int b = z & 3, var = z >> 2;
  const ushort* xT = (var == 0) ? xq : (var == 1) ? xk : xv;
  const float* bias = (var == 0) ? b0 : (var == 1) ? b1 : b2;
  ushort* outp = (var == 0) ? o0 : (var == 1) ? o1 : o2;
  const float scale = (var == 0) ? QS : 1.0f;
  conv_body<128>(xT + (size_t)b * (LPAD * CC), Wt + (size_t)var * CC * KK, bias, outp,
                 (var == 2) ? 1 : 0, b, scale);
}

// ---------------------------------------------------------------------------
// Attention v13 (ROUND-8 PROVEN, 61.4 us attn / 242.1 us total — BEST).
// EXACT REVERT after v14 (full V-in-reg: spills, 156 us) and v15 (half
// V-in-reg: uncoalesced per-lane V loads, 86 us) both regressed.  Model:
// tile period 4605 cyc == LDS-pipe work (16 waves x ~270 cyc + 384 conflict)
// -> this structure is at its LDS roofline; every LDS-reduction variant
// re-exposes VMEM latency or uncoalesced throughput (v8/v10/v11/v14/v15).
// 512 threads = 8 waves x 16 Q-rows; K/V dbuf via global_load_lds, 1
// barrier/tile; S^T = K Q^T; denominator via ones-MFMA; Q pre-scaled (QS)
// so softmax is a bare exp2; setprio(1) around MFMA clusters (+drifted-wave
// regime); direct padded-transposed output.
// ---------------------------------------------------------------------------
__global__ __launch_bounds__(512, 4)
void attn_k(const ushort* __restrict__ qh, const ushort* __restrict__ kh,
            const ushort* __restrict__ vt, ushort* __restrict__ obT)
{
  const int id   = blockIdx.x;
  const int xcd  = id & 7;
  const int slot = id >> 3;          // 0..63
  const int bh   = xcd * 4 + (slot >> 4);
  const int x0   = (slot & 15) * 128;
  const int b = bh >> 3, h = bh & 7;
  const int tid = threadIdx.x, lane = tid & 63, wv = tid >> 6;   // wv 0..7
  const int col = lane & 15, quad = lane >> 4;
  const int wx = wv * 16;            // wave-private Q rows / P rows
  const int c7 = col & 7;

  __shared__ ushort Kv[2][8192];     // [buf][ K 64x64 | V^T 64x64 ]  32 KB
  __shared__ ushort Ps[128 * 88];    // 22.5 KB  (P[x][y], stride 88)

  const ushort* Qg = qh + (size_t)bh * (LL * HD);
  const ushort* Kg = kh + (size_t)bh * (LL * HD);
  const ushort* Vg = vt + (size_t)bh * (HD * LL);
  ushort* ob = obT + (size_t)b * (LPAD * CC);

  const int sr = tid >> 3;                 // 0..63
  const int g8 = ((tid & 7) ^ (sr & 7)) * 8;

  // Q fragments (lane&15 = x-row, k = quad*8+j) — valid as A or B operand
  bf16x8 aq[2];
#pragma unroll
  for (int kk = 0; kk < 2; ++kk)
    aq[kk] = *(const bf16x8*)(Qg + (size_t)(x0 + wx + col) * HD + kk * 32 + quad * 8);

  const short one = (short)0x3F80;  // bf16 1.0
  const bf16x8 ones = {one, one, one, one, one, one, one, one};

  f32x4 oacc[4] = {};
  f32x4 dacc = {};

  // prefetch y-tile 0 into buf 0 (512 threads: 1 K-load + 1 V-load each)
  {
    gload16(Kg + (size_t)sr * HD + g8, &Kv[0][tid * 8]);
    gload16(Vg + (size_t)sr * LL + g8, &Kv[0][4096 + tid * 8]);
  }

  for (int yt = 0; yt < 32; ++yt) {
    const int cur = yt & 1;
    __syncthreads();
    if (yt + 1 < 32) {
      const int y1 = (yt + 1) * 64;
      gload16(Kg + (size_t)(y1 + sr) * HD + g8, &Kv[1 - cur][tid * 8]);
      gload16(Vg + (size_t)sr * LL + y1 + g8, &Kv[1 - cur][4096 + tid * 8]);
    }
    const ushort* Kb = &Kv[cur][0];
    const ushort* Vb = &Kv[cur][4096];

    // S^T = K Q^T : C rows (quad*4+r) = y-local, cols = x-local
    f32x4 sacc[4] = {};
    __builtin_amdgcn_s_setprio(1);
#pragma unroll
    for (int kk = 0; kk < 2; ++kk)
#pragma unroll
      for (int j = 0; j < 4; ++j) {
        bf16x8 bk = *(const bf16x8*)&Kb[(j * 16 + col) * 64 + (((kk * 4 + quad) ^ c7) * 8)];
        sacc[j] = __builtin_amdgcn_mfma_f32_16x16x32_bf16(bk, aq[kk], sacc[j], 0, 0, 0);
      }
    __builtin_amdgcn_s_setprio(0);
    // exp2 + pack 4 consecutive-y bf16 -> one ds_write_b64 per j
#pragma unroll
    for (int j = 0; j < 4; ++j) {
      union { __hip_bfloat162 h[2]; uint2 u; } pk;
      pk.h[0] = __float22bfloat162_rn(make_float2(__builtin_amdgcn_exp2f(sacc[j][0]),
                                                 __builtin_amdgcn_exp2f(sacc[j][1])));
      pk.h[1] = __float22bfloat162_rn(make_float2(__builtin_amdgcn_exp2f(sacc[j][2]),
                                                 __builtin_amdgcn_exp2f(sacc[j][3])));
      *(uint2*)&Ps[(wx + col) * 88 + j * 16 + quad * 4] = pk.u;
    }
    // O += P V ; denom += P * ones  (wave reads only its own Ps rows)
    __builtin_amdgcn_s_setprio(1);
#pragma unroll
    for (int kk = 0; kk < 2; ++kk) {
      bf16x8 ap = *(const bf16x8*)&Ps[(wx + col) * 88 + kk * 32 + quad * 8];
      dacc = __builtin_amdgcn_mfma_f32_16x16x32_bf16(ap, ones, dacc, 0, 0, 0);
#pragma unroll
      for (int j = 0; j < 4; ++j) {
        bf16x8 bv = *(const bf16x8*)&Vb[(j * 16 + col) * 64 + (((kk * 4 + quad) ^ c7) * 8)];
        oacc[j] = __builtin_amdgcn_mfma_f32_16x16x32_bf16(ap, bv, oacc[j], 0, 0, 0);
      }
    }
    __builtin_amdgcn_s_setprio(0);
  }

  // normalize + scatter DIRECTLY to padded-transposed [b][l+1][c] bf16
#pragma unroll
  for (int r = 0; r < 4; ++r) {
    const int xg = x0 + wx + quad * 4 + r;
    const float inv = 1.f / dacc[r];
#pragma unroll
    for (int j = 0; j < 4; ++j) {
      const int d = j * 16 + col;
      const int flat = xg * 512 + h * 64 + d;
      const int c = flat >> 11, l = flat & 2047;
      ob[(size_t)(l + 1) * CC + c] = f2bf(oacc[j][r] * inv);
    }
  }
  if ((slot & 15) == 0 && tid < 128) {
    const int rw = tid >> 6;
    const int cc = h * 64 + (tid & 63);
    ob[(size_t)(rw ? (LPAD - 1) : 0) * CC + cc] = 0;
  }
}

// ---------------------------------------------------------------------------
extern "C" void kernel_launch(void* const* d_in, const int* in_sizes, int n_in,
                              void* d_out, int out_size, void* d_ws, size_t ws_size,
                              hipStream_t stream) {
  const float* q    = (const float*)d_in[0];
  const float* k    = (const float*)d_in[1];
  const float* v    = (const float*)d_in[2];
  const float* wq_w = (const float*)d_in[3];
  const float* wq_b = (const float*)d_in[4];
  const float* wk_w = (const float*)d_in[5];
  const float* wk_b = (const float*)d_in[6];
  const float* wv_w = (const float*)d_in[7];
  const float* wv_b = (const float*)d_in[8];
  const float* fc_w = (const float*)d_in[9];
  const float* fc_b = (const float*)d_in[10];

  char* ws = (char*)d_ws;
  const size_t WSZ = (size_t)CC * KK * sizeof(ushort);            // 1.5 MB per conv
  const size_t HSZ = (size_t)BB * NH * LL * HD * sizeof(ushort);  // 8.39 MB per head tensor
  const size_t XSZ = (size_t)BB * LPAD * CC * sizeof(ushort);     // 8.40 MB padded xT
  const size_t FUSED_NEED = 4 * WSZ + 3 * HSZ + 3 * XSZ;          // ~56.65 MB

  ushort* Wt = (ushort*)(ws);
  prep_w<<<(4 * CC * KK + 255) / 256, 256, 0, stream>>>(wq_w, wk_w, wv_w, fc_w, Wt);

  if (ws_size >= FUSED_NEED) {
    ushort* qh  = (ushort*)(ws + 4 * WSZ);
    ushort* kh  = (ushort*)(ws + 4 * WSZ + HSZ);
    ushort* vt  = (ushort*)(ws + 4 * WSZ + 2 * HSZ);
    ushort* xTq = (ushort*)(ws + 4 * WSZ + 3 * HSZ);
    ushort* xTk = (ushort*)(ws + 4 * WSZ + 3 * HSZ + XSZ);
    ushort* xTv = (ushort*)(ws + 4 * WSZ + 3 * HSZ + 2 * XSZ);
    ushort* obT = xTq;                  // attn output (xTq dead after conv3)

    transpose3_k<<<dim3(32, 8, 12), 256, 0, stream>>>(q, k, v, xTq, xTk, xTv);
    conv3_k<<<dim3(16, 4, 12), 256, 0, stream>>>(xTq, xTk, xTv, Wt,
                                                 wq_b, wk_b, wv_b, qh, kh, vt);
    attn_k<<<512, 512, 0, stream>>>(qh, kh, vt, obT);
    conv_k<64><<<dim3(16, 8, 4), 256, 0, stream>>>(obT, Wt + 3 * CC * KK, fc_b,
                                                   (float*)d_out, 2, 1.0f);
  } else {
    ushort* qh  = (ushort*)(ws + 4 * WSZ);
    ushort* kh  = (ushort*)(ws + 4 * WSZ + HSZ);
    ushort* vt  = (ushort*)(ws + 4 * WSZ + 2 * HSZ);
    ushort* xTb = (ushort*)(ws + 4 * WSZ + 3 * HSZ);
    ushort* obT = xTb;

    transpose_k<<<dim3(32, 8, 4), 256, 0, stream>>>(q, xTb);
    conv_k<128><<<dim3(16, 4, 4), 256, 0, stream>>>(xTb, Wt + 0 * CC * KK, wq_b, qh, 0, QS);
    transpose_k<<<dim3(32, 8, 4), 256, 0, stream>>>(k, xTb);
    conv_k<128><<<dim3(16, 4, 4), 256, 0, stream>>>(xTb, Wt + 1 * CC * KK, wk_b, kh, 0, 1.0f);
    transpose_k<<<dim3(32, 8, 4), 256, 0, stream>>>(v, xTb);
    conv_k<128><<<dim3(16, 4, 4), 256, 0, stream>>>(xTb, Wt + 2 * CC * KK, wv_b, vt, 1, 1.0f);
    attn_k<<<512, 512, 0, stream>>>(qh, kh, vt, obT);
    conv_k<64><<<dim3(16, 8, 4), 256, 0, stream>>>(obT, Wt + 3 * CC * KK, fc_b,
                                                   (float*)d_out, 2, 1.0f);
  }
}

// Round 12
// 246.519 us; speedup vs baseline: 1.3725x; 1.0383x over previous
//
#include <hip/hip_runtime.h>
#include <hip/hip_bf16.h>

#define BB 4
#define NH 8
#define HD 64
#define CC 512
#define LL 2048
#define KK 1536   // C*3, K index = t*512 + ci
#define LPAD 2050 // padded rows of xT: row 0 and row 2049 are zeros

// softmax scale folded into q-conv: exp(S/64) == exp2(S * log2(e)/64)
#define QS 0.022542110013890054f

typedef float f32x4 __attribute__((ext_vector_type(4)));
typedef short bf16x8 __attribute__((ext_vector_type(8)));

static __device__ __forceinline__ ushort f2bf(float f) {
  union { float f; unsigned u; } v; v.f = f;
  unsigned r = v.u + 0x7fffu + ((v.u >> 16) & 1u);   // RNE
  return (ushort)(r >> 16);
}
static __device__ __forceinline__ void gload16(const ushort* g, ushort* l) {
  __builtin_amdgcn_global_load_lds((const __attribute__((address_space(1))) void*)g,
                                   (__attribute__((address_space(3))) void*)l, 16, 0, 0);
}

// ---------------------------------------------------------------------------
// Weight prep: W[co][ci][t] fp32 -> W'[co][t*512+ci] bf16, for all 4 convs.
// Vectorized 8 elems/thread: an 8-aligned kk-chunk never crosses a tap
// boundary (512 | chunk starts), so t is uniform per chunk; writes are one
// aligned uint4 (16 B) per thread.  1536 blocks vs the old scalar 12288.
// ---------------------------------------------------------------------------
__global__ void prep_w(const float* __restrict__ w0, const float* __restrict__ w1,
                       const float* __restrict__ w2, const float* __restrict__ w3,
                       ushort* __restrict__ out)
{
  const int per8 = CC * KK / 8;            // 98304 chunks per conv
  int i8 = blockIdx.x * 256 + threadIdx.x;
  if (i8 >= 4 * per8) return;
  int cidx = i8 / per8;
  int rem  = i8 - cidx * per8;
  int co   = rem / (KK / 8);
  int kc   = (rem - co * (KK / 8)) * 8;    // kk base, multiple of 8
  int t = kc >> 9, ci = kc & 511;
  const float* w = (cidx == 0) ? w0 : (cidx == 1) ? w1 : (cidx == 2) ? w2 : w3;
  const float* src = w + ((size_t)co * CC + ci) * 3 + t;
  ushort s[8];
#pragma unroll
  for (int e = 0; e < 8; ++e) s[e] = f2bf(src[e * 3]);
  *(uint4*)&out[(size_t)i8 * 8] = *(uint4*)s;
}

// ---------------------------------------------------------------------------
// Transpose+cast body: xb[c][l] fp32 -> ob[l+1][c] bf16, zero halo rows.
// ---------------------------------------------------------------------------
__device__ __forceinline__ void transpose_body(const float* __restrict__ xb,
                                               ushort* __restrict__ ob)
{
  const int c0 = blockIdx.y * 64;
  const int l0 = blockIdx.x * 64;
  const int tid = threadIdx.x;
  __shared__ ushort T[64 * 72];
  {
    const int rr = tid >> 4;      // 0..15
    const int f4 = tid & 15;      // 0..15
#pragma unroll
    for (int it = 0; it < 4; ++it) {
      const int cc = rr + it * 16;
      ushort s[4];
      float4 vv = *(const float4*)(xb + (size_t)(c0 + cc) * LL + l0 + f4 * 4);
      s[0] = f2bf(vv.x); s[1] = f2bf(vv.y); s[2] = f2bf(vv.z); s[3] = f2bf(vv.w);
      *(ushort4*)&T[cc * 72 + f4 * 4] = *(ushort4*)s;
    }
  }
  __syncthreads();
  {
    const int lr = tid >> 3;     // 0..31
    const int ch = tid & 7;      // 0..7
#pragma unroll
    for (int it = 0; it < 2; ++it) {
      const int ll = lr + it * 32;
      ushort tmp[8];
#pragma unroll
      for (int e = 0; e < 8; ++e) tmp[e] = T[(ch * 8 + e) * 72 + ll];
      *(uint4*)(ob + (size_t)(l0 + ll + 1) * CC + c0 + ch * 8) = *(uint4*)tmp;
    }
  }
  if (blockIdx.x == 0 && tid < 8) {
    uint4 z4 = make_uint4(0, 0, 0, 0);
    *(uint4*)(ob + c0 + tid * 8) = z4;
  }
  if (blockIdx.x == (LL / 64 - 1) && tid >= 248) {
    uint4 z4 = make_uint4(0, 0, 0, 0);
    *(uint4*)(ob + (size_t)(LPAD - 1) * CC + c0 + (tid - 248) * 8) = z4;
  }
}

__global__ __launch_bounds__(256, 4)
void transpose_k(const float* __restrict__ in, ushort* __restrict__ outT)
{
  const int b = blockIdx.z;
  transpose_body(in + (size_t)b * CC * LL, outT + (size_t)b * (LPAD * CC));
}

__global__ __launch_bounds__(256, 4)
void transpose3_k(const float* __restrict__ q, const float* __restrict__ k,
                  const float* __restrict__ v, ushort* __restrict__ xq,
                  ushort* __restrict__ xk, ushort* __restrict__ xv)
{
  const int z = blockIdx.z;
  const int b = z & 3, var = z >> 2;
  const float* in = (var == 0) ? q : (var == 1) ? k : v;
  ushort* out = (var == 0) ? xq : (var == 1) ? xk : xv;
  transpose_body(in + (size_t)b * CC * LL, out + (size_t)b * (LPAD * CC));
}

// ---------------------------------------------------------------------------
// conv1d(k=3,same) as implicit GEMM — ROUND-6 PROVEN STRUCTURE, templated on
// BM (output-channel tile).  BM=128: qkv convs, grid (16,4,12) = 3 blocks/CU.
// BM=64: fc conv, grid (16,8,4) = 512 blocks = 2 blocks/CU.  BK=64,
// single-buffer 2-barrier, (BM/32+4)x global_load_lds(16B)/thread, XOR chunk
// swizzle on the global fetch address, (BM/32)*4*2 MFMA/wave per iter.
// mode 0: heads [b][h][x][d] bf16 (q,k) | 1: heads-T [b][h][d][x] bf16 (v)
// mode 2: [b][co][l] fp32 (final fc)
// scale: folded into epilogue (QS for the q conv so attn can use raw exp2).
// ---------------------------------------------------------------------------
template<int BM>
__device__ __forceinline__ void conv_body(const ushort* __restrict__ xb,
                                          const ushort* __restrict__ Wt,
                                          const float* __restrict__ bias,
                                          void* __restrict__ outp, int mode, int b,
                                          float scale)
{
  const int co0 = blockIdx.y * BM;
  const int l0  = blockIdx.x * 128;
  const int tid = threadIdx.x;
  const int lane = tid & 63;
  const int w    = tid >> 6;
  const int col  = lane & 15, quad = lane >> 4;
  constexpr int MI = BM / 32;              // i-tiles per wave

  __shared__ ushort Asl[BM * 64];
  __shared__ ushort Bsl[128 * 64];

  const int sr = tid >> 3;                 // 0..31
  const int g8 = ((tid & 7) ^ (sr & 7)) * 8;
  const ushort* ag  = Wt + (size_t)(co0 + sr) * KK + g8;
  const ushort* bg  = xb + (size_t)(l0 + sr) * CC + g8;
  ushort* alds = &Asl[tid * 8];
  ushort* blds = &Bsl[tid * 8];

  f32x4 acc[MI][4] = {};
  const int wm = (w & 1) * (BM / 2);
  const int wn = (w >> 1) * 64;
  const int c7 = col & 7;

  for (int k0 = 0; k0 < KK; k0 += 64) {
#pragma unroll
    for (int r2 = 0; r2 < MI; ++r2)
      gload16(ag + (size_t)(r2 * 32) * KK + k0, alds + r2 * 2048);
#pragma unroll
    for (int r2 = 0; r2 < 4; ++r2)
      gload16(bg + (size_t)(r2 * 32) * CC + k0, blds + r2 * 2048);
    __syncthreads();
#pragma unroll
    for (int kk = 0; kk < 2; ++kk) {
      bf16x8 af[MI], bfr[4];
#pragma unroll
      for (int i = 0; i < MI; ++i)
        af[i] = *(const bf16x8*)&Asl[(wm + i * 16 + col) * 64 + (((kk * 4 + quad) ^ c7) * 8)];
#pragma unroll
      for (int j = 0; j < 4; ++j)
        bfr[j] = *(const bf16x8*)&Bsl[(wn + j * 16 + col) * 64 + (((kk * 4 + quad) ^ c7) * 8)];
#pragma unroll
      for (int i = 0; i < MI; ++i)
#pragma unroll
        for (int j = 0; j < 4; ++j)
          acc[i][j] = __builtin_amdgcn_mfma_f32_16x16x32_bf16(af[i], bfr[j], acc[i][j], 0, 0, 0);
    }
    __syncthreads();
  }

  // epilogue: C/D layout row = quad*4+r (co), col = lane&15 (l)
#pragma unroll
  for (int i = 0; i < MI; ++i) {
#pragma unroll
    for (int r = 0; r < 4; ++r) {
      const int co = co0 + wm + i * 16 + quad * 4 + r;
      const float bi = bias[co];
#pragma unroll
      for (int j = 0; j < 4; ++j) {
        const int l = l0 + wn + j * 16 + col;
        const float y = (acc[i][j][r] + bi) * scale;
        if (mode == 0) {
          const int xx = (co << 2) + (l >> 9);
          const int hh = (l >> 6) & 7;
          const int dd = l & 63;
          ((ushort*)outp)[((size_t)(b * NH + hh) * LL + xx) * HD + dd] = f2bf(y);
        } else if (mode == 1) {
          const int xx = (co << 2) + (l >> 9);
          const int hh = (l >> 6) & 7;
          const int dd = l & 63;
          ((ushort*)outp)[((size_t)(b * NH + hh) * HD + dd) * LL + xx] = f2bf(y);
        } else {
          ((float*)outp)[(size_t)(b * CC + co) * LL + l] = y;
        }
      }
    }
  }
}

template<int BM>
__global__ __launch_bounds__(256, 3)
void conv_k(const ushort* __restrict__ xT, const ushort* __restrict__ Wt,
            const float* __restrict__ bias, void* __restrict__ outp, int mode,
            float scale)
{
  const int b = blockIdx.z;
  conv_body<BM>(xT + (size_t)b * (LPAD * CC), Wt, bias, outp, mode, b, scale);
}

__global__ __launch_bounds__(256, 3)
void conv3_k(const ushort* __restrict__ xq, const ushort* __restrict__ xk,
             const ushort* __restrict__ xv, const ushort* __restrict__ Wt,
             const float* __restrict__ b0, const float* __restrict__ b1,
             const float* __restrict__ b2, ushort* __restrict__ o0,
             ushort* __restrict__ o1, ushort* __restrict__ o2)
{
  const int z = blockIdx.z;
  const int b = z & 3, var = z >> 2;
  const ushort* xT = (var == 0) ? xq : (var == 1) ? xk : xv;
  const float* bias = (var == 0) ? b0 : (var == 1) ? b1 : b2;
  ushort* outp = (var == 0) ? o0 : (var == 1) ? o1 : o2;
  const float scale = (var == 0) ? QS : 1.0f;
  conv_body<128>(xT + (size_t)b * (LPAD * CC), Wt + (size_t)var * CC * KK, bias, outp,
                 (var == 2) ? 1 : 0, b, scale);
}

// ---------------------------------------------------------------------------
// Attention v13 (ROUND-8 PROVEN BEST: 58.7-61.4 us attn / 242.1 us total).
// Family local optimum — 5 structural alternatives regressed (v8 L1-direct
// -3.8x, v10 32x32 -8%, v11 reg-P -17%, v14 V-in-reg spills -2.5x, v15
// half-V-in-reg uncoalesced -40%).  512 threads = 8 waves x 16 Q-rows; K/V
// dbuf via global_load_lds, 1 barrier/tile; S^T = K Q^T; denominator via
// ones-MFMA; Q pre-scaled (QS) so softmax is a bare exp2; setprio(1) around
// MFMA clusters; direct padded-transposed output.
// ---------------------------------------------------------------------------
__global__ __launch_bounds__(512, 4)
void attn_k(const ushort* __restrict__ qh, const ushort* __restrict__ kh,
            const ushort* __restrict__ vt, ushort* __restrict__ obT)
{
  const int id   = blockIdx.x;
  const int xcd  = id & 7;
  const int slot = id >> 3;          // 0..63
  const int bh   = xcd * 4 + (slot >> 4);
  const int x0   = (slot & 15) * 128;
  const int b = bh >> 3, h = bh & 7;
  const int tid = threadIdx.x, lane = tid & 63, wv = tid >> 6;   // wv 0..7
  const int col = lane & 15, quad = lane >> 4;
  const int wx = wv * 16;            // wave-private Q rows / P rows
  const int c7 = col & 7;

  __shared__ ushort Kv[2][8192];     // [buf][ K 64x64 | V^T 64x64 ]  32 KB
  __shared__ ushort Ps[128 * 88];    // 22.5 KB  (P[x][y], stride 88)

  const ushort* Qg = qh + (size_t)bh * (LL * HD);
  const ushort* Kg = kh + (size_t)bh * (LL * HD);
  const ushort* Vg = vt + (size_t)bh * (HD * LL);
  ushort* ob = obT + (size_t)b * (LPAD * CC);

  const int sr = tid >> 3;                 // 0..63
  const int g8 = ((tid & 7) ^ (sr & 7)) * 8;

  // Q fragments (lane&15 = x-row, k = quad*8+j) — valid as A or B operand
  bf16x8 aq[2];
#pragma unroll
  for (int kk = 0; kk < 2; ++kk)
    aq[kk] = *(const bf16x8*)(Qg + (size_t)(x0 + wx + col) * HD + kk * 32 + quad * 8);

  const short one = (short)0x3F80;  // bf16 1.0
  const bf16x8 ones = {one, one, one, one, one, one, one, one};

  f32x4 oacc[4] = {};
  f32x4 dacc = {};

  // prefetch y-tile 0 into buf 0 (512 threads: 1 K-load + 1 V-load each)
  {
    gload16(Kg + (size_t)sr * HD + g8, &Kv[0][tid * 8]);
    gload16(Vg + (size_t)sr * LL + g8, &Kv[0][4096 + tid * 8]);
  }

  for (int yt = 0; yt < 32; ++yt) {
    const int cur = yt & 1;
    __syncthreads();
    if (yt + 1 < 32) {
      const int y1 = (yt + 1) * 64;
      gload16(Kg + (size_t)(y1 + sr) * HD + g8, &Kv[1 - cur][tid * 8]);
      gload16(Vg + (size_t)sr * LL + y1 + g8, &Kv[1 - cur][4096 + tid * 8]);
    }
    const ushort* Kb = &Kv[cur][0];
    const ushort* Vb = &Kv[cur][4096];

    // S^T = K Q^T : C rows (quad*4+r) = y-local, cols = x-local
    f32x4 sacc[4] = {};
    __builtin_amdgcn_s_setprio(1);
#pragma unroll
    for (int kk = 0; kk < 2; ++kk)
#pragma unroll
      for (int j = 0; j < 4; ++j) {
        bf16x8 bk = *(const bf16x8*)&Kb[(j * 16 + col) * 64 + (((kk * 4 + quad) ^ c7) * 8)];
        sacc[j] = __builtin_amdgcn_mfma_f32_16x16x32_bf16(bk, aq[kk], sacc[j], 0, 0, 0);
      }
    __builtin_amdgcn_s_setprio(0);
    // exp2 + pack 4 consecutive-y bf16 -> one ds_write_b64 per j
#pragma unroll
    for (int j = 0; j < 4; ++j) {
      union { __hip_bfloat162 h[2]; uint2 u; } pk;
      pk.h[0] = __float22bfloat162_rn(make_float2(__builtin_amdgcn_exp2f(sacc[j][0]),
                                                 __builtin_amdgcn_exp2f(sacc[j][1])));
      pk.h[1] = __float22bfloat162_rn(make_float2(__builtin_amdgcn_exp2f(sacc[j][2]),
                                                 __builtin_amdgcn_exp2f(sacc[j][3])));
      *(uint2*)&Ps[(wx + col) * 88 + j * 16 + quad * 4] = pk.u;
    }
    // O += P V ; denom += P * ones  (wave reads only its own Ps rows)
    __builtin_amdgcn_s_setprio(1);
#pragma unroll
    for (int kk = 0; kk < 2; ++kk) {
      bf16x8 ap = *(const bf16x8*)&Ps[(wx + col) * 88 + kk * 32 + quad * 8];
      dacc = __builtin_amdgcn_mfma_f32_16x16x32_bf16(ap, ones, dacc, 0, 0, 0);
#pragma unroll
      for (int j = 0; j < 4; ++j) {
        bf16x8 bv = *(const bf16x8*)&Vb[(j * 16 + col) * 64 + (((kk * 4 + quad) ^ c7) * 8)];
        oacc[j] = __builtin_amdgcn_mfma_f32_16x16x32_bf16(ap, bv, oacc[j], 0, 0, 0);
      }
    }
    __builtin_amdgcn_s_setprio(0);
  }

  // normalize + scatter DIRECTLY to padded-transposed [b][l+1][c] bf16
#pragma unroll
  for (int r = 0; r < 4; ++r) {
    const int xg = x0 + wx + quad * 4 + r;
    const float inv = 1.f / dacc[r];
#pragma unroll
    for (int j = 0; j < 4; ++j) {
      const int d = j * 16 + col;
      const int flat = xg * 512 + h * 64 + d;
      const int c = flat >> 11, l = flat & 2047;
      ob[(size_t)(l + 1) * CC + c] = f2bf(oacc[j][r] * inv);
    }
  }
  if ((slot & 15) == 0 && tid < 128) {
    const int rw = tid >> 6;
    const int cc = h * 64 + (tid & 63);
    ob[(size_t)(rw ? (LPAD - 1) : 0) * CC + cc] = 0;
  }
}

// ---------------------------------------------------------------------------
extern "C" void kernel_launch(void* const* d_in, const int* in_sizes, int n_in,
                              void* d_out, int out_size, void* d_ws, size_t ws_size,
                              hipStream_t stream) {
  const float* q    = (const float*)d_in[0];
  const float* k    = (const float*)d_in[1];
  const float* v    = (const float*)d_in[2];
  const float* wq_w = (const float*)d_in[3];
  const float* wq_b = (const float*)d_in[4];
  const float* wk_w = (const float*)d_in[5];
  const float* wk_b = (const float*)d_in[6];
  const float* wv_w = (const float*)d_in[7];
  const float* wv_b = (const float*)d_in[8];
  const float* fc_w = (const float*)d_in[9];
  const float* fc_b = (const float*)d_in[10];

  char* ws = (char*)d_ws;
  const size_t WSZ = (size_t)CC * KK * sizeof(ushort);            // 1.5 MB per conv
  const size_t HSZ = (size_t)BB * NH * LL * HD * sizeof(ushort);  // 8.39 MB per head tensor
  const size_t XSZ = (size_t)BB * LPAD * CC * sizeof(ushort);     // 8.40 MB padded xT
  const size_t FUSED_NEED = 4 * WSZ + 3 * HSZ + 3 * XSZ;          // ~56.65 MB

  ushort* Wt = (ushort*)(ws);
  prep_w<<<(4 * CC * KK / 8 + 255) / 256, 256, 0, stream>>>(wq_w, wk_w, wv_w, fc_w, Wt);

  if (ws_size >= FUSED_NEED) {
    ushort* qh  = (ushort*)(ws + 4 * WSZ);
    ushort* kh  = (ushort*)(ws + 4 * WSZ + HSZ);
    ushort* vt  = (ushort*)(ws + 4 * WSZ + 2 * HSZ);
    ushort* xTq = (ushort*)(ws + 4 * WSZ + 3 * HSZ);
    ushort* xTk = (ushort*)(ws + 4 * WSZ + 3 * HSZ + XSZ);
    ushort* xTv = (ushort*)(ws + 4 * WSZ + 3 * HSZ + 2 * XSZ);
    ushort* obT = xTq;                  // attn output (xTq dead after conv3)

    transpose3_k<<<dim3(32, 8, 12), 256, 0, stream>>>(q, k, v, xTq, xTk, xTv);
    conv3_k<<<dim3(16, 4, 12), 256, 0, stream>>>(xTq, xTk, xTv, Wt,
                                                 wq_b, wk_b, wv_b, qh, kh, vt);
    attn_k<<<512, 512, 0, stream>>>(qh, kh, vt, obT);
    conv_k<64><<<dim3(16, 8, 4), 256, 0, stream>>>(obT, Wt + 3 * CC * KK, fc_b,
                                                   (float*)d_out, 2, 1.0f);
  } else {
    ushort* qh  = (ushort*)(ws + 4 * WSZ);
    ushort* kh  = (ushort*)(ws + 4 * WSZ + HSZ);
    ushort* vt  = (ushort*)(ws + 4 * WSZ + 2 * HSZ);
    ushort* xTb = (ushort*)(ws + 4 * WSZ + 3 * HSZ);
    ushort* obT = xTb;

    transpose_k<<<dim3(32, 8, 4), 256, 0, stream>>>(q, xTb);
    conv_k<128><<<dim3(16, 4, 4), 256, 0, stream>>>(xTb, Wt + 0 * CC * KK, wq_b, qh, 0, QS);
    transpose_k<<<dim3(32, 8, 4), 256, 0, stream>>>(k, xTb);
    conv_k<128><<<dim3(16, 4, 4), 256, 0, stream>>>(xTb, Wt + 1 * CC * KK, wk_b, kh, 0, 1.0f);
    transpose_k<<<dim3(32, 8, 4), 256, 0, stream>>>(v, xTb);
    conv_k<128><<<dim3(16, 4, 4), 256, 0, stream>>>(xTb, Wt + 2 * CC * KK, wv_b, vt, 1, 1.0f);
    attn_k<<<512, 512, 0, stream>>>(qh, kh, vt, obT);
    conv_k<64><<<dim3(16, 8, 4), 256, 0, stream>>>(obT, Wt + 3 * CC * KK, fc_b,
                                                   (float*)d_out, 2, 1.0f);
  }
}